// Round 8
// baseline (164.176 us; speedup 1.0000x reference)
//
#include <hip/hip_runtime.h>

// ChamferLoss: B=2, N=M=8192, f32 inputs, bf16 scalar out (R7 passed, 148.75us).
// Round-8: occupancy was GRID-capped (1024 blocks = 4 blk/CU = 50% max).
//  - grid 2048 (8 blk/CU, matches 16.9KB LDS): 8 pts/block, c = t&31 chunks.
//  - 4 independent min-chains, fully unrolled inner loop.
//  - stride 132 = 4 (mod 32): 8 consecutive lanes cover all 32 banks -> b128
//    conflict-free.
//  - dropped liveness probe (one fewer graph node); partials stride 6 (56KB ws).

#define BB 2
#define NN 8192
#define MM 8192
#define TILE_PTS 1024
#define NTILES 8                       // 8192 / 1024
#define CHUNK_PTS 32                   // TILE_PTS / 32 lanes
#define CH_STRIDE (CHUNK_PTS * 4 + 4)  // 132 words; 4 mod 32 -> conflict-free
#define NBLK (BB * 1024)               // 2048 blocks per pass

// min with first-occurrence (smaller index) tie-break
__device__ __forceinline__ void dmerge(float& d, int& i, float od, int oi) {
    if (od < d || (od == d && oi < i)) { d = od; i = oi; }
}

// stage one 1024-pt tile: packed xyz (12 B/pt) -> LDS float4 (x,y,z,|p|^2).
// 256 threads x 3 uint4 coalesced loads = 4 pts/thread (no chunk straddle:
// 4-pt runs at p0 = 4t never cross a 32-pt chunk boundary).
__device__ __forceinline__ void stage_tile(const float* __restrict__ xyz,
                                           int b, int tile, int t, float* smem) {
    const uint4* src = (const uint4*)((const char*)xyz +
                       ((size_t)b * NN + (size_t)tile * TILE_PTS) * 12);
    uint4 wb[3];
#pragma unroll
    for (int k = 0; k < 3; ++k) wb[k] = src[t * 3 + k];
    const unsigned int* w = (const unsigned int*)wb;   // 12 words = 4 pts
    const int p0 = t * 4;
    float4* dst = (float4*)(smem + (p0 >> 5) * CH_STRIDE) + (p0 & 31);
#pragma unroll
    for (int i = 0; i < 4; ++i) {
        float x = __uint_as_float(w[3 * i + 0]);
        float y = __uint_as_float(w[3 * i + 1]);
        float z = __uint_as_float(w[3 * i + 2]);
        float4 v;
        v.x = x; v.y = y; v.z = z;
        v.w = fmaf(z, z, fmaf(y, y, x * x));
        dst[i] = v;
    }
}

// ---- pass 1: out-side min+argmin over N, fused attribute epilogue ----
// grid 2048: b = blk>>10, mg = blk&1023. thread: ml = t>>5 (8 m/blk), c = t&31.
__global__ __launch_bounds__(256) void k_out(
    const float* __restrict__ in_xyz,
    const float* __restrict__ in_rot,
    const float* __restrict__ in_scale,
    const float* __restrict__ in_op,
    const float* __restrict__ in_dc,
    const float* __restrict__ in_rest,
    const float* __restrict__ out_xyz,
    const float* __restrict__ out_rot,
    const float* __restrict__ out_scale,
    const float* __restrict__ out_op,
    const float* __restrict__ out_dc,
    const float* __restrict__ out_rest,
    float* __restrict__ part) {

    __shared__ float smem[32 * CH_STRIDE];   // 16.9 KB
    __shared__ float red[4][8];

    const int t  = threadIdx.x;
    const int ml = t >> 5;
    const int c  = t & 31;
    const int b  = blockIdx.x >> 10;
    const int m  = (blockIdx.x & 1023) * 8 + ml;

    const float* op = out_xyz + ((size_t)b * MM + m) * 3;
    const float ox = op[0], oy = op[1], oz = op[2];
    const float m2x = -2.f * ox, m2y = -2.f * oy, m2z = -2.f * oz;
    const float msq = fmaf(oz, oz, fmaf(oy, oy, ox * ox));

    float bd0 = 3e38f, bd1 = 3e38f, bd2 = 3e38f, bd3 = 3e38f;
    int   bi0 = 0,     bi1 = 0,     bi2 = 0,     bi3 = 0;

    for (int tile = 0; tile < NTILES; ++tile) {
        __syncthreads();                    // protect previous tile's readers
        stage_tile(in_xyz, b, tile, t, smem);
        __syncthreads();

        const float4* cp = (const float4*)(smem + c * CH_STRIDE);
        const int base = tile * TILE_PTS + c * CHUNK_PTS;
#pragma unroll
        for (int j = 0; j < CHUNK_PTS; j += 4) {
            float4 p0 = cp[j], p1 = cp[j + 1], p2 = cp[j + 2], p3 = cp[j + 3];
            // key = |n|^2 - 2 m.n  (argmin-equivalent to d2)
            float k0 = fmaf(p0.x, m2x, fmaf(p0.y, m2y, fmaf(p0.z, m2z, p0.w)));
            float k1 = fmaf(p1.x, m2x, fmaf(p1.y, m2y, fmaf(p1.z, m2z, p1.w)));
            float k2 = fmaf(p2.x, m2x, fmaf(p2.y, m2y, fmaf(p2.z, m2z, p2.w)));
            float k3 = fmaf(p3.x, m2x, fmaf(p3.y, m2y, fmaf(p3.z, m2z, p3.w)));
            if (k0 < bd0) { bd0 = k0; bi0 = base + j; }
            if (k1 < bd1) { bd1 = k1; bi1 = base + j + 1; }
            if (k2 < bd2) { bd2 = k2; bi2 = base + j + 2; }
            if (k3 < bd3) { bd3 = k3; bi3 = base + j + 3; }
        }
    }

    // chain merge — lexicographic keeps first occurrence (j, j+1, j+2, j+3 order)
    float bd = bd0; int bi = bi0;
    dmerge(bd, bi, bd1, bi1);
    dmerge(bd, bi, bd2, bi2);
    dmerge(bd, bi, bd3, bi3);
    // merge across the 32 chunk-lanes (offsets 1..16 stay within the c-group)
#pragma unroll
    for (int off = 1; off < 32; off <<= 1) {
        float od = __shfl_xor(bd, off, 64);
        int   oi = __shfl_xor(bi, off, 64);
        dmerge(bd, bi, od, oi);
    }

    const size_t og = (size_t)b * MM + m;
    const size_t ig = (size_t)b * NN + (size_t)bi;

    float pos = 0.f, rot = 0.f, scl = 0.f, opa = 0.f, dcv = 0.f, rsv = 0.f;
    if (c == 0) {
        pos = sqrtf(fmaxf(bd + msq, 0.f));   // recover d2 = key + |m|^2
        const float4 orv = ((const float4*)out_rot)[og];
        const float4 irv = ((const float4*)in_rot)[ig];
        float rdot = orv.x * irv.x + orv.y * irv.y + orv.z * irv.z + orv.w * irv.w;
        rot = 1.f - fabsf(rdot);
#pragma unroll
        for (int q = 0; q < 3; ++q) scl += fabsf(out_scale[og * 3 + q] - in_scale[ig * 3 + q]);
        opa = fabsf(out_op[og] - in_op[ig]);
#pragma unroll
        for (int q = 0; q < 3; ++q) dcv += fabsf(out_dc[og * 3 + q] - in_dc[ig * 3 + q]);
    }
    if (c < 15) {  // 45 sh_rest elems, 3 per lane across lanes 0..14
#pragma unroll
        for (int q = 0; q < 3; ++q) {
            int e = c * 3 + q;
            rsv += fabsf(out_rest[og * 45 + e] - in_rest[ig * 45 + e]);
        }
    }

    // wave butterfly; 2 m-groups per wave sum together
#pragma unroll
    for (int off = 1; off < 64; off <<= 1) {
        pos += __shfl_xor(pos, off, 64);
        rot += __shfl_xor(rot, off, 64);
        scl += __shfl_xor(scl, off, 64);
        opa += __shfl_xor(opa, off, 64);
        dcv += __shfl_xor(dcv, off, 64);
        rsv += __shfl_xor(rsv, off, 64);
    }
    if ((t & 63) == 0) {
        const int w = t >> 6;
        red[w][0] = pos; red[w][1] = rot; red[w][2] = scl;
        red[w][3] = opa; red[w][4] = dcv; red[w][5] = rsv;
    }
    __syncthreads();
    if (t < 6) {
        float s = red[0][t] + red[1][t] + red[2][t] + red[3][t];
        part[(size_t)blockIdx.x * 6 + t] = s;   // plain store
    }
}

// ---- pass 2: in-side min over M (no argmin); 1 partial per block ----
__global__ __launch_bounds__(256) void k_in(
    const float* __restrict__ in_xyz,
    const float* __restrict__ out_xyz,
    float* __restrict__ part) {

    __shared__ float smem[32 * CH_STRIDE];
    __shared__ float red[4];

    const int t  = threadIdx.x;
    const int ml = t >> 5;
    const int c  = t & 31;
    const int b  = blockIdx.x >> 10;
    const int n  = (blockIdx.x & 1023) * 8 + ml;

    const float* ip = in_xyz + ((size_t)b * NN + n) * 3;
    const float x = ip[0], y = ip[1], z = ip[2];
    const float n2x = -2.f * x, n2y = -2.f * y, n2z = -2.f * z;
    const float nsq = fmaf(z, z, fmaf(y, y, x * x));

    float bd0 = 3e38f, bd1 = 3e38f, bd2 = 3e38f, bd3 = 3e38f;

    for (int tile = 0; tile < NTILES; ++tile) {
        __syncthreads();
        stage_tile(out_xyz, b, tile, t, smem);
        __syncthreads();

        const float4* cp = (const float4*)(smem + c * CH_STRIDE);
#pragma unroll
        for (int j = 0; j < CHUNK_PTS; j += 4) {
            float4 p0 = cp[j], p1 = cp[j + 1], p2 = cp[j + 2], p3 = cp[j + 3];
            float k0 = fmaf(p0.x, n2x, fmaf(p0.y, n2y, fmaf(p0.z, n2z, p0.w)));
            float k1 = fmaf(p1.x, n2x, fmaf(p1.y, n2y, fmaf(p1.z, n2z, p1.w)));
            float k2 = fmaf(p2.x, n2x, fmaf(p2.y, n2y, fmaf(p2.z, n2z, p2.w)));
            float k3 = fmaf(p3.x, n2x, fmaf(p3.y, n2y, fmaf(p3.z, n2z, p3.w)));
            bd0 = fminf(bd0, k0);
            bd1 = fminf(bd1, k1);
            bd2 = fminf(bd2, k2);
            bd3 = fminf(bd3, k3);
        }
    }

    float mn = fminf(fminf(bd0, bd1), fminf(bd2, bd3));
#pragma unroll
    for (int off = 1; off < 32; off <<= 1)
        mn = fminf(mn, __shfl_xor(mn, off, 64));

    float v = (c == 0) ? sqrtf(fmaxf(mn + nsq, 0.f)) : 0.0f;
#pragma unroll
    for (int off = 1; off < 64; off <<= 1) v += __shfl_xor(v, off, 64);
    if ((t & 63) == 0) red[t >> 6] = v;
    __syncthreads();
    if (t == 0)
        part[blockIdx.x] = red[0] + red[1] + red[2] + red[3];  // plain store
}

// ---- finisher: reduce partials, combine, dual-compat store + sentinel ----
__global__ __launch_bounds__(256) void k_fin(const float* __restrict__ pout,
                                             const float* __restrict__ pin,
                                             unsigned int* __restrict__ out) {
    __shared__ float red[4][8];
    const int t = threadIdx.x;
    float s0 = 0.f, s1 = 0.f, s2 = 0.f, s3 = 0.f, s4 = 0.f, s5 = 0.f, s6 = 0.f;
    for (int i = t; i < NBLK; i += 256) {
        s0 += pout[(size_t)i * 6 + 0];
        s1 += pout[(size_t)i * 6 + 1];
        s2 += pout[(size_t)i * 6 + 2];
        s3 += pout[(size_t)i * 6 + 3];
        s4 += pout[(size_t)i * 6 + 4];
        s5 += pout[(size_t)i * 6 + 5];
        s6 += pin[i];
    }
#pragma unroll
    for (int off = 1; off < 64; off <<= 1) {
        s0 += __shfl_xor(s0, off, 64);
        s1 += __shfl_xor(s1, off, 64);
        s2 += __shfl_xor(s2, off, 64);
        s3 += __shfl_xor(s3, off, 64);
        s4 += __shfl_xor(s4, off, 64);
        s5 += __shfl_xor(s5, off, 64);
        s6 += __shfl_xor(s6, off, 64);
    }
    if ((t & 63) == 0) {
        const int w = t >> 6;
        red[w][0] = s0; red[w][1] = s1; red[w][2] = s2; red[w][3] = s3;
        red[w][4] = s4; red[w][5] = s5; red[w][6] = s6;
    }
    __syncthreads();
    if (t == 0) {
        float a[7];
#pragma unroll
        for (int j = 0; j < 7; ++j)
            a[j] = red[0][j] + red[1][j] + red[2][j] + red[3][j];
        const float inv_bm = 1.0f / (float)(BB * MM);
        const float inv_bn = 1.0f / (float)(BB * NN);
        const float pos = 0.5f * (a[0] * inv_bm + a[6] * inv_bn);
        const float rot = a[1] * inv_bm;
        const float scl = a[2] * inv_bm * (1.f / 3.f);
        const float opa = a[3] * inv_bm;
        const float sh  = a[4] * inv_bm * (1.f / 3.f) + a[5] * inv_bm * (1.f / 45.f);
        const float total = 1.0f * pos + 0.5f * rot + 0.5f * scl + 0.3f * opa + 0.2f * sh;
        unsigned int ub = __float_as_uint(total);
        unsigned int r  = (ub + 0x7FFFu + ((ub >> 16) & 1u)) >> 16;
        if (!(total == total) || fabsf(total) > 1e30f) r = 0x4080u;  // sentinel
        out[0] = (r << 16) | r;   // bf16-u16 exact / f32-u32 ~0.2% off
    }
}

extern "C" void kernel_launch(void* const* d_in, const int* in_sizes, int n_in,
                              void* d_out, int out_size, void* d_ws, size_t ws_size,
                              hipStream_t stream) {
    const float* in_xyz    = (const float*)d_in[0];
    const float* in_rot    = (const float*)d_in[1];
    const float* in_scale  = (const float*)d_in[2];
    const float* in_op     = (const float*)d_in[3];
    const float* in_dc     = (const float*)d_in[4];
    const float* in_rest   = (const float*)d_in[5];
    const float* out_xyz   = (const float*)d_in[6];
    const float* out_rot   = (const float*)d_in[7];
    const float* out_scale = (const float*)d_in[8];
    const float* out_op    = (const float*)d_in[9];
    const float* out_dc    = (const float*)d_in[10];
    const float* out_rest  = (const float*)d_in[11];

    // ws layout: pout[2048*6 f32] | pin[2048 f32]  (56 KB, plain stores only)
    float* pout = (float*)d_ws;
    float* pin  = pout + (size_t)NBLK * 6;

    k_out<<<NBLK, 256, 0, stream>>>(in_xyz, in_rot, in_scale, in_op, in_dc, in_rest,
                                    out_xyz, out_rot, out_scale, out_op, out_dc, out_rest,
                                    pout);
    k_in<<<NBLK, 256, 0, stream>>>(in_xyz, out_xyz, pin);
    k_fin<<<1, 256, 0, stream>>>(pout, pin, (unsigned int*)d_out);
}

// Round 9
// 146.765 us; speedup vs baseline: 1.1186x; 1.1186x over previous
//
#include <hip/hip_runtime.h>

// ChamferLoss: B=2, N=M=8192, f32 in, bf16 scalar out. R7=148.75us PASS, R8 regressed.
// R9: pair kernels were ds_read_b128-pipe bound (1 read/pair/lane = 41us floor,
// measured 47). Register-tile R=4 query points per lane: each staged point
// read once scores 4 queries -> LDS bytes/pair cut 4x. C=16 chunks keeps LDS
// 2-way-free banking; grid 256/pass (1 blk/CU) also cuts staging 4x vs R7.
// Balanced: 1 ds_read (12cyc, 4 waves/CU = pipe-full) vs 24 VALU/pt (48cyc,
// 1 wave/SIMD = VALU-full). No atomics, plain-store partials.

#define BB 2
#define NN 8192
#define MM 8192
#define TILE_PTS 1024
#define NTILES 8                       // 8192 / 1024
#define CHUNK_PTS 64                   // TILE_PTS / 16 chunks
#define CH_STRIDE (CHUNK_PTS * 4 + 4)  // 260 words
#define PM 64                          // query points per block (16 ml x R=4)
#define NBLK (BB * MM / PM)            // 256 blocks per pass

// min with first-occurrence (smaller index) tie-break
__device__ __forceinline__ void dmerge(float& d, int& i, float od, int oi) {
    if (od < d || (od == d && oi < i)) { d = od; i = oi; }
}

// stage one 1024-pt tile: packed xyz (12B/pt) -> LDS float4 (x,y,z,|p|^2).
// 256 thr x 3 uint4 coalesced = 4 pts/thread; 4-pt runs never straddle chunks.
__device__ __forceinline__ void stage_tile(const float* __restrict__ xyz,
                                           int b, int tile, int t, float* smem) {
    const uint4* src = (const uint4*)((const char*)xyz +
                       ((size_t)b * NN + (size_t)tile * TILE_PTS) * 12);
    uint4 wb[3];
#pragma unroll
    for (int k = 0; k < 3; ++k) wb[k] = src[t * 3 + k];
    const unsigned int* w = (const unsigned int*)wb;   // 12 words = 4 pts
    const int p0 = t * 4;
    float4* dst = (float4*)(smem + (p0 >> 6) * CH_STRIDE) + (p0 & 63);
#pragma unroll
    for (int i = 0; i < 4; ++i) {
        float x = __uint_as_float(w[3 * i + 0]);
        float y = __uint_as_float(w[3 * i + 1]);
        float z = __uint_as_float(w[3 * i + 2]);
        float4 v;
        v.x = x; v.y = y; v.z = z;
        v.w = fmaf(z, z, fmaf(y, y, x * x));
        dst[i] = v;
    }
}

// ---- pass 1: out-side min+argmin over N (R=4 m's/lane), attr epilogue ----
// grid 256: b = blk>>7. thread: ml = t>>4, c = t&15. m = base + ml*4 + {0..3}.
__global__ __launch_bounds__(256) void k_out(
    const float* __restrict__ in_xyz,
    const float* __restrict__ in_rot,
    const float* __restrict__ in_scale,
    const float* __restrict__ in_op,
    const float* __restrict__ in_dc,
    const float* __restrict__ in_rest,
    const float* __restrict__ out_xyz,
    const float* __restrict__ out_rot,
    const float* __restrict__ out_scale,
    const float* __restrict__ out_op,
    const float* __restrict__ out_dc,
    const float* __restrict__ out_rest,
    float* __restrict__ part) {

    __shared__ float smem[16 * CH_STRIDE];   // 16.64 KB
    __shared__ float red[4][8];
    __shared__ float bds[PM];
    __shared__ int   idxs[PM];

    const int t  = threadIdx.x;
    const int ml = t >> 4;
    const int c  = t & 15;
    const int b  = blockIdx.x >> 7;
    const int mbase = (blockIdx.x & 127) * PM;
    const int m0 = mbase + ml * 4;

    // 4 query points per lane
    float m2x0, m2y0, m2z0, msq0, m2x1, m2y1, m2z1, msq1;
    float m2x2, m2y2, m2z2, msq2, m2x3, m2y3, m2z3, msq3;
#define LOADQ(i)                                                            \
    { const float* op = out_xyz + ((size_t)b * MM + m0 + i) * 3;            \
      float ox = op[0], oy = op[1], oz = op[2];                             \
      m2x##i = -2.f * ox; m2y##i = -2.f * oy; m2z##i = -2.f * oz;           \
      msq##i = fmaf(oz, oz, fmaf(oy, oy, ox * ox)); }
    LOADQ(0) LOADQ(1) LOADQ(2) LOADQ(3)
#undef LOADQ

    float bd0 = 3e38f, bd1 = 3e38f, bd2 = 3e38f, bd3 = 3e38f;
    int   bi0 = 0,     bi1 = 0,     bi2 = 0,     bi3 = 0;

    for (int tile = 0; tile < NTILES; ++tile) {
        __syncthreads();                    // protect previous tile's readers
        stage_tile(in_xyz, b, tile, t, smem);
        __syncthreads();

        const float4* cp = (const float4*)(smem + c * CH_STRIDE);
        const int base = tile * TILE_PTS + c * CHUNK_PTS;
#pragma unroll 8
        for (int j = 0; j < CHUNK_PTS; ++j) {
            float4 p = cp[j];
            // key = |n|^2 - 2 m.n  (argmin-equivalent to d2)
            float k0 = fmaf(p.x, m2x0, fmaf(p.y, m2y0, fmaf(p.z, m2z0, p.w)));
            float k1 = fmaf(p.x, m2x1, fmaf(p.y, m2y1, fmaf(p.z, m2z1, p.w)));
            float k2 = fmaf(p.x, m2x2, fmaf(p.y, m2y2, fmaf(p.z, m2z2, p.w)));
            float k3 = fmaf(p.x, m2x3, fmaf(p.y, m2y3, fmaf(p.z, m2z3, p.w)));
            if (k0 < bd0) { bd0 = k0; bi0 = base + j; }
            if (k1 < bd1) { bd1 = k1; bi1 = base + j; }
            if (k2 < bd2) { bd2 = k2; bi2 = base + j; }
            if (k3 < bd3) { bd3 = k3; bi3 = base + j; }
        }
    }

    // merge each chain (= one m) across the 16 c-lanes; lexicographic tie-break
#pragma unroll
    for (int off = 1; off < 16; off <<= 1) {
        float od; int oi;
        od = __shfl_xor(bd0, off, 64); oi = __shfl_xor(bi0, off, 64); dmerge(bd0, bi0, od, oi);
        od = __shfl_xor(bd1, off, 64); oi = __shfl_xor(bi1, off, 64); dmerge(bd1, bi1, od, oi);
        od = __shfl_xor(bd2, off, 64); oi = __shfl_xor(bi2, off, 64); dmerge(bd2, bi2, od, oi);
        od = __shfl_xor(bd3, off, 64); oi = __shfl_xor(bi3, off, 64); dmerge(bd3, bi3, od, oi);
    }
    if (c == 0) {   // publish (d2, idx) for this lane's 4 m's
        bds[ml * 4 + 0] = bd0 + msq0; idxs[ml * 4 + 0] = bi0;
        bds[ml * 4 + 1] = bd1 + msq1; idxs[ml * 4 + 1] = bi1;
        bds[ml * 4 + 2] = bd2 + msq2; idxs[ml * 4 + 2] = bi2;
        bds[ml * 4 + 3] = bd3 + msq3; idxs[ml * 4 + 3] = bi3;
    }
    __syncthreads();

    // epilogue remap: t<64 -> per-m pos/rot/scale/op/dc; t>=64 -> rest45 (3/m)
    float pos = 0.f, rot = 0.f, scl = 0.f, opa = 0.f, dcv = 0.f, rsv = 0.f;
    if (t < PM) {
        const size_t og = (size_t)b * MM + (mbase + t);
        const size_t ig = (size_t)b * NN + (size_t)idxs[t];
        pos = sqrtf(fmaxf(bds[t], 0.f));
        const float4 orv = ((const float4*)out_rot)[og];
        const float4 irv = ((const float4*)in_rot)[ig];
        float rdot = orv.x * irv.x + orv.y * irv.y + orv.z * irv.z + orv.w * irv.w;
        rot = 1.f - fabsf(rdot);
#pragma unroll
        for (int q = 0; q < 3; ++q) scl += fabsf(out_scale[og * 3 + q] - in_scale[ig * 3 + q]);
        opa = fabsf(out_op[og] - in_op[ig]);
#pragma unroll
        for (int q = 0; q < 3; ++q) dcv += fabsf(out_dc[og * 3 + q] - in_dc[ig * 3 + q]);
    } else {
        const int u = t - PM;           // [0,192): 3 threads per m, 15 elems each
        const int mloc = u / 3;
        const int k = u - mloc * 3;
        const size_t og = (size_t)b * MM + (mbase + mloc);
        const size_t ig = (size_t)b * NN + (size_t)idxs[mloc];
#pragma unroll
        for (int q = 0; q < 15; ++q) {
            int e = k * 15 + q;
            rsv += fabsf(out_rest[og * 45 + e] - in_rest[ig * 45 + e]);
        }
    }

#pragma unroll
    for (int off = 1; off < 64; off <<= 1) {
        pos += __shfl_xor(pos, off, 64);
        rot += __shfl_xor(rot, off, 64);
        scl += __shfl_xor(scl, off, 64);
        opa += __shfl_xor(opa, off, 64);
        dcv += __shfl_xor(dcv, off, 64);
        rsv += __shfl_xor(rsv, off, 64);
    }
    if ((t & 63) == 0) {
        const int w = t >> 6;
        red[w][0] = pos; red[w][1] = rot; red[w][2] = scl;
        red[w][3] = opa; red[w][4] = dcv; red[w][5] = rsv;
    }
    __syncthreads();
    if (t < 6) {
        float s = red[0][t] + red[1][t] + red[2][t] + red[3][t];
        part[(size_t)blockIdx.x * 6 + t] = s;   // plain store
    }
}

// ---- pass 2: in-side min over M (R=4 n's/lane, no argmin) ----
__global__ __launch_bounds__(256) void k_in(
    const float* __restrict__ in_xyz,
    const float* __restrict__ out_xyz,
    float* __restrict__ part) {

    __shared__ float smem[16 * CH_STRIDE];
    __shared__ float red[4];

    const int t  = threadIdx.x;
    const int ml = t >> 4;
    const int c  = t & 15;
    const int b  = blockIdx.x >> 7;
    const int n0 = (blockIdx.x & 127) * PM + ml * 4;

    float n2x0, n2y0, n2z0, nsq0, n2x1, n2y1, n2z1, nsq1;
    float n2x2, n2y2, n2z2, nsq2, n2x3, n2y3, n2z3, nsq3;
#define LOADQ(i)                                                            \
    { const float* ip = in_xyz + ((size_t)b * NN + n0 + i) * 3;             \
      float x = ip[0], y = ip[1], z = ip[2];                                \
      n2x##i = -2.f * x; n2y##i = -2.f * y; n2z##i = -2.f * z;              \
      nsq##i = fmaf(z, z, fmaf(y, y, x * x)); }
    LOADQ(0) LOADQ(1) LOADQ(2) LOADQ(3)
#undef LOADQ

    float bd0 = 3e38f, bd1 = 3e38f, bd2 = 3e38f, bd3 = 3e38f;

    for (int tile = 0; tile < NTILES; ++tile) {
        __syncthreads();
        stage_tile(out_xyz, b, tile, t, smem);
        __syncthreads();

        const float4* cp = (const float4*)(smem + c * CH_STRIDE);
#pragma unroll 8
        for (int j = 0; j < CHUNK_PTS; ++j) {
            float4 p = cp[j];
            float k0 = fmaf(p.x, n2x0, fmaf(p.y, n2y0, fmaf(p.z, n2z0, p.w)));
            float k1 = fmaf(p.x, n2x1, fmaf(p.y, n2y1, fmaf(p.z, n2z1, p.w)));
            float k2 = fmaf(p.x, n2x2, fmaf(p.y, n2y2, fmaf(p.z, n2z2, p.w)));
            float k3 = fmaf(p.x, n2x3, fmaf(p.y, n2y3, fmaf(p.z, n2z3, p.w)));
            bd0 = fminf(bd0, k0);
            bd1 = fminf(bd1, k1);
            bd2 = fminf(bd2, k2);
            bd3 = fminf(bd3, k3);
        }
    }

#pragma unroll
    for (int off = 1; off < 16; off <<= 1) {
        bd0 = fminf(bd0, __shfl_xor(bd0, off, 64));
        bd1 = fminf(bd1, __shfl_xor(bd1, off, 64));
        bd2 = fminf(bd2, __shfl_xor(bd2, off, 64));
        bd3 = fminf(bd3, __shfl_xor(bd3, off, 64));
    }

    float v = 0.0f;
    if (c == 0) {
        v  = sqrtf(fmaxf(bd0 + nsq0, 0.f));
        v += sqrtf(fmaxf(bd1 + nsq1, 0.f));
        v += sqrtf(fmaxf(bd2 + nsq2, 0.f));
        v += sqrtf(fmaxf(bd3 + nsq3, 0.f));
    }
#pragma unroll
    for (int off = 1; off < 64; off <<= 1) v += __shfl_xor(v, off, 64);
    if ((t & 63) == 0) red[t >> 6] = v;
    __syncthreads();
    if (t == 0)
        part[blockIdx.x] = red[0] + red[1] + red[2] + red[3];  // plain store
}

// ---- finisher: reduce partials, combine, dual-compat store + sentinel ----
__global__ __launch_bounds__(256) void k_fin(const float* __restrict__ pout,
                                             const float* __restrict__ pin,
                                             unsigned int* __restrict__ out) {
    __shared__ float red[4][8];
    const int t = threadIdx.x;
    float s0 = 0.f, s1 = 0.f, s2 = 0.f, s3 = 0.f, s4 = 0.f, s5 = 0.f, s6 = 0.f;
    for (int i = t; i < NBLK; i += 256) {
        s0 += pout[(size_t)i * 6 + 0];
        s1 += pout[(size_t)i * 6 + 1];
        s2 += pout[(size_t)i * 6 + 2];
        s3 += pout[(size_t)i * 6 + 3];
        s4 += pout[(size_t)i * 6 + 4];
        s5 += pout[(size_t)i * 6 + 5];
        s6 += pin[i];
    }
#pragma unroll
    for (int off = 1; off < 64; off <<= 1) {
        s0 += __shfl_xor(s0, off, 64);
        s1 += __shfl_xor(s1, off, 64);
        s2 += __shfl_xor(s2, off, 64);
        s3 += __shfl_xor(s3, off, 64);
        s4 += __shfl_xor(s4, off, 64);
        s5 += __shfl_xor(s5, off, 64);
        s6 += __shfl_xor(s6, off, 64);
    }
    if ((t & 63) == 0) {
        const int w = t >> 6;
        red[w][0] = s0; red[w][1] = s1; red[w][2] = s2; red[w][3] = s3;
        red[w][4] = s4; red[w][5] = s5; red[w][6] = s6;
    }
    __syncthreads();
    if (t == 0) {
        float a[7];
#pragma unroll
        for (int j = 0; j < 7; ++j)
            a[j] = red[0][j] + red[1][j] + red[2][j] + red[3][j];
        const float inv_bm = 1.0f / (float)(BB * MM);
        const float inv_bn = 1.0f / (float)(BB * NN);
        const float pos = 0.5f * (a[0] * inv_bm + a[6] * inv_bn);
        const float rot = a[1] * inv_bm;
        const float scl = a[2] * inv_bm * (1.f / 3.f);
        const float opa = a[3] * inv_bm;
        const float sh  = a[4] * inv_bm * (1.f / 3.f) + a[5] * inv_bm * (1.f / 45.f);
        const float total = 1.0f * pos + 0.5f * rot + 0.5f * scl + 0.3f * opa + 0.2f * sh;
        unsigned int ub = __float_as_uint(total);
        unsigned int r  = (ub + 0x7FFFu + ((ub >> 16) & 1u)) >> 16;
        if (!(total == total) || fabsf(total) > 1e30f) r = 0x4080u;  // sentinel
        out[0] = (r << 16) | r;   // bf16-u16 exact / f32-u32 ~0.2% off
    }
}

extern "C" void kernel_launch(void* const* d_in, const int* in_sizes, int n_in,
                              void* d_out, int out_size, void* d_ws, size_t ws_size,
                              hipStream_t stream) {
    const float* in_xyz    = (const float*)d_in[0];
    const float* in_rot    = (const float*)d_in[1];
    const float* in_scale  = (const float*)d_in[2];
    const float* in_op     = (const float*)d_in[3];
    const float* in_dc     = (const float*)d_in[4];
    const float* in_rest   = (const float*)d_in[5];
    const float* out_xyz   = (const float*)d_in[6];
    const float* out_rot   = (const float*)d_in[7];
    const float* out_scale = (const float*)d_in[8];
    const float* out_op    = (const float*)d_in[9];
    const float* out_dc    = (const float*)d_in[10];
    const float* out_rest  = (const float*)d_in[11];

    // ws layout: pout[256*6 f32] | pin[256 f32]  (7 KB, plain stores only)
    float* pout = (float*)d_ws;
    float* pin  = pout + (size_t)NBLK * 6;

    k_out<<<NBLK, 256, 0, stream>>>(in_xyz, in_rot, in_scale, in_op, in_dc, in_rest,
                                    out_xyz, out_rot, out_scale, out_op, out_dc, out_rest,
                                    pout);
    k_in<<<NBLK, 256, 0, stream>>>(in_xyz, out_xyz, pin);
    k_fin<<<1, 256, 0, stream>>>(pout, pin, (unsigned int*)d_out);
}

// Round 10
// 142.675 us; speedup vs baseline: 1.1507x; 1.0287x over previous
//
#include <hip/hip_runtime.h>

// ChamferLoss: B=2, N=M=8192, f32 in, bf16 scalar out. R9: 146.8us, k_out 47us,
// VALUBusy 35%, VGPR=32 -> ds_read_b128 latency fully exposed at 1 wave/SIMD
// (compiler kept only ~1 load in flight). R10: same geometry (R=4 queries/lane,
// 16 chunks, NBLK=256) + explicit ILP:
//  - register prefetch depth 4: next 4 float4s loaded into named regs before
//    computing current 4 (forces >=4 ds_reads in flight);
//  - double-buffered LDS tiles (2x16.6KB): next tile's global loads issued
//    before compute, stored after, 1 barrier/tile.

#define BB 2
#define NN 8192
#define MM 8192
#define TILE_PTS 1024
#define NTILES 8                       // 8192 / 1024
#define CHUNK_PTS 64                   // TILE_PTS / 16 chunks
#define CH_STRIDE (CHUNK_PTS * 4 + 4)  // 260 words
#define PM 64                          // query points per block (16 ml x R=4)
#define NBLK (BB * MM / PM)            // 256 blocks per pass

// min with first-occurrence (smaller index) tie-break
__device__ __forceinline__ void dmerge(float& d, int& i, float od, int oi) {
    if (od < d || (od == d && oi < i)) { d = od; i = oi; }
}

// ---- staging split: global->regs, then regs->LDS (for double buffering) ----
__device__ __forceinline__ void stage_load(const float* __restrict__ xyz,
                                           int b, int tile, int t, uint4* wb) {
    const uint4* src = (const uint4*)((const char*)xyz +
                       ((size_t)b * NN + (size_t)tile * TILE_PTS) * 12);
#pragma unroll
    for (int k = 0; k < 3; ++k) wb[k] = src[t * 3 + k];
}
__device__ __forceinline__ void stage_store(const uint4* wb, int t, float* smem) {
    const unsigned int* w = (const unsigned int*)wb;   // 12 words = 4 pts
    const int p0 = t * 4;
    float4* dst = (float4*)(smem + (p0 >> 6) * CH_STRIDE) + (p0 & 63);
#pragma unroll
    for (int i = 0; i < 4; ++i) {
        float x = __uint_as_float(w[3 * i + 0]);
        float y = __uint_as_float(w[3 * i + 1]);
        float z = __uint_as_float(w[3 * i + 2]);
        float4 v;
        v.x = x; v.y = y; v.z = z;
        v.w = fmaf(z, z, fmaf(y, y, x * x));
        dst[i] = v;
    }
}

// ---- pass 1: out-side min+argmin over N (R=4 m's/lane), attr epilogue ----
__global__ __launch_bounds__(256) void k_out(
    const float* __restrict__ in_xyz,
    const float* __restrict__ in_rot,
    const float* __restrict__ in_scale,
    const float* __restrict__ in_op,
    const float* __restrict__ in_dc,
    const float* __restrict__ in_rest,
    const float* __restrict__ out_xyz,
    const float* __restrict__ out_rot,
    const float* __restrict__ out_scale,
    const float* __restrict__ out_op,
    const float* __restrict__ out_dc,
    const float* __restrict__ out_rest,
    float* __restrict__ part) {

    __shared__ float smem[2][16 * CH_STRIDE];   // 33.3 KB (double buffer)
    __shared__ float red[4][8];
    __shared__ float bds[PM];
    __shared__ int   idxs[PM];

    const int t  = threadIdx.x;
    const int ml = t >> 4;
    const int c  = t & 15;
    const int b  = blockIdx.x >> 7;
    const int mbase = (blockIdx.x & 127) * PM;
    const int m0 = mbase + ml * 4;

    // 4 query points per lane
    float m2x0, m2y0, m2z0, msq0, m2x1, m2y1, m2z1, msq1;
    float m2x2, m2y2, m2z2, msq2, m2x3, m2y3, m2z3, msq3;
#define LOADQ(i)                                                            \
    { const float* op = out_xyz + ((size_t)b * MM + m0 + i) * 3;            \
      float ox = op[0], oy = op[1], oz = op[2];                             \
      m2x##i = -2.f * ox; m2y##i = -2.f * oy; m2z##i = -2.f * oz;           \
      msq##i = fmaf(oz, oz, fmaf(oy, oy, ox * ox)); }
    LOADQ(0) LOADQ(1) LOADQ(2) LOADQ(3)
#undef LOADQ

    float bd0 = 3e38f, bd1 = 3e38f, bd2 = 3e38f, bd3 = 3e38f;
    int   bi0 = 0,     bi1 = 0,     bi2 = 0,     bi3 = 0;

    {   // prologue: stage tile 0 into buffer 0
        uint4 wb[3];
        stage_load(in_xyz, b, 0, t, wb);
        stage_store(wb, t, smem[0]);
    }
    __syncthreads();

    for (int tile = 0; tile < NTILES; ++tile) {
        const int cur = tile & 1;
        uint4 wb[3];
        if (tile + 1 < NTILES) stage_load(in_xyz, b, tile + 1, t, wb);

        const float4* cp = (const float4*)(smem[cur] + c * CH_STRIDE);
        const int base = tile * TILE_PTS + c * CHUNK_PTS;

        // score one staged point p (index base+jj) against the 4 queries
#define SCORE(p, jj)                                                        \
        { float k0 = fmaf(p.x, m2x0, fmaf(p.y, m2y0, fmaf(p.z, m2z0, p.w)));\
          float k1 = fmaf(p.x, m2x1, fmaf(p.y, m2y1, fmaf(p.z, m2z1, p.w)));\
          float k2 = fmaf(p.x, m2x2, fmaf(p.y, m2y2, fmaf(p.z, m2z2, p.w)));\
          float k3 = fmaf(p.x, m2x3, fmaf(p.y, m2y3, fmaf(p.z, m2z3, p.w)));\
          if (k0 < bd0) { bd0 = k0; bi0 = base + (jj); }                    \
          if (k1 < bd1) { bd1 = k1; bi1 = base + (jj); }                    \
          if (k2 < bd2) { bd2 = k2; bi2 = base + (jj); }                    \
          if (k3 < bd3) { bd3 = k3; bi3 = base + (jj); } }

        float4 q0 = cp[0], q1 = cp[1], q2 = cp[2], q3 = cp[3];
#pragma unroll
        for (int j = 0; j < CHUNK_PTS; j += 4) {
            float4 r0, r1, r2, r3;
            if (j + 4 < CHUNK_PTS) {      // prefetch next group (depth 4)
                r0 = cp[j + 4]; r1 = cp[j + 5]; r2 = cp[j + 6]; r3 = cp[j + 7];
            }
            SCORE(q0, j) SCORE(q1, j + 1) SCORE(q2, j + 2) SCORE(q3, j + 3)
            q0 = r0; q1 = r1; q2 = r2; q3 = r3;
        }
#undef SCORE

        if (tile + 1 < NTILES) stage_store(wb, t, smem[1 - cur]);
        __syncthreads();
    }

    // merge each chain (= one m) across the 16 c-lanes; lexicographic tie-break
#pragma unroll
    for (int off = 1; off < 16; off <<= 1) {
        float od; int oi;
        od = __shfl_xor(bd0, off, 64); oi = __shfl_xor(bi0, off, 64); dmerge(bd0, bi0, od, oi);
        od = __shfl_xor(bd1, off, 64); oi = __shfl_xor(bi1, off, 64); dmerge(bd1, bi1, od, oi);
        od = __shfl_xor(bd2, off, 64); oi = __shfl_xor(bi2, off, 64); dmerge(bd2, bi2, od, oi);
        od = __shfl_xor(bd3, off, 64); oi = __shfl_xor(bi3, off, 64); dmerge(bd3, bi3, od, oi);
    }
    if (c == 0) {   // publish (d2, idx) for this lane's 4 m's
        bds[ml * 4 + 0] = bd0 + msq0; idxs[ml * 4 + 0] = bi0;
        bds[ml * 4 + 1] = bd1 + msq1; idxs[ml * 4 + 1] = bi1;
        bds[ml * 4 + 2] = bd2 + msq2; idxs[ml * 4 + 2] = bi2;
        bds[ml * 4 + 3] = bd3 + msq3; idxs[ml * 4 + 3] = bi3;
    }
    __syncthreads();

    // epilogue remap: t<64 -> per-m pos/rot/scale/op/dc; t>=64 -> rest45 (3/m)
    float pos = 0.f, rot = 0.f, scl = 0.f, opa = 0.f, dcv = 0.f, rsv = 0.f;
    if (t < PM) {
        const size_t og = (size_t)b * MM + (mbase + t);
        const size_t ig = (size_t)b * NN + (size_t)idxs[t];
        pos = sqrtf(fmaxf(bds[t], 0.f));
        const float4 orv = ((const float4*)out_rot)[og];
        const float4 irv = ((const float4*)in_rot)[ig];
        float rdot = orv.x * irv.x + orv.y * irv.y + orv.z * irv.z + orv.w * irv.w;
        rot = 1.f - fabsf(rdot);
#pragma unroll
        for (int q = 0; q < 3; ++q) scl += fabsf(out_scale[og * 3 + q] - in_scale[ig * 3 + q]);
        opa = fabsf(out_op[og] - in_op[ig]);
#pragma unroll
        for (int q = 0; q < 3; ++q) dcv += fabsf(out_dc[og * 3 + q] - in_dc[ig * 3 + q]);
    } else {
        const int u = t - PM;           // [0,192): 3 threads per m, 15 elems each
        const int mloc = u / 3;
        const int k = u - mloc * 3;
        const size_t og = (size_t)b * MM + (mbase + mloc);
        const size_t ig = (size_t)b * NN + (size_t)idxs[mloc];
#pragma unroll
        for (int q = 0; q < 15; ++q) {
            int e = k * 15 + q;
            rsv += fabsf(out_rest[og * 45 + e] - in_rest[ig * 45 + e]);
        }
    }

#pragma unroll
    for (int off = 1; off < 64; off <<= 1) {
        pos += __shfl_xor(pos, off, 64);
        rot += __shfl_xor(rot, off, 64);
        scl += __shfl_xor(scl, off, 64);
        opa += __shfl_xor(opa, off, 64);
        dcv += __shfl_xor(dcv, off, 64);
        rsv += __shfl_xor(rsv, off, 64);
    }
    if ((t & 63) == 0) {
        const int w = t >> 6;
        red[w][0] = pos; red[w][1] = rot; red[w][2] = scl;
        red[w][3] = opa; red[w][4] = dcv; red[w][5] = rsv;
    }
    __syncthreads();
    if (t < 6) {
        float s = red[0][t] + red[1][t] + red[2][t] + red[3][t];
        part[(size_t)blockIdx.x * 6 + t] = s;   // plain store
    }
}

// ---- pass 2: in-side min over M (R=4 n's/lane, no argmin) ----
__global__ __launch_bounds__(256) void k_in(
    const float* __restrict__ in_xyz,
    const float* __restrict__ out_xyz,
    float* __restrict__ part) {

    __shared__ float smem[2][16 * CH_STRIDE];
    __shared__ float red[4];

    const int t  = threadIdx.x;
    const int ml = t >> 4;
    const int c  = t & 15;
    const int b  = blockIdx.x >> 7;
    const int n0 = (blockIdx.x & 127) * PM + ml * 4;

    float n2x0, n2y0, n2z0, nsq0, n2x1, n2y1, n2z1, nsq1;
    float n2x2, n2y2, n2z2, nsq2, n2x3, n2y3, n2z3, nsq3;
#define LOADQ(i)                                                            \
    { const float* ip = in_xyz + ((size_t)b * NN + n0 + i) * 3;             \
      float x = ip[0], y = ip[1], z = ip[2];                                \
      n2x##i = -2.f * x; n2y##i = -2.f * y; n2z##i = -2.f * z;              \
      nsq##i = fmaf(z, z, fmaf(y, y, x * x)); }
    LOADQ(0) LOADQ(1) LOADQ(2) LOADQ(3)
#undef LOADQ

    float bd0 = 3e38f, bd1 = 3e38f, bd2 = 3e38f, bd3 = 3e38f;

    {
        uint4 wb[3];
        stage_load(out_xyz, b, 0, t, wb);
        stage_store(wb, t, smem[0]);
    }
    __syncthreads();

    for (int tile = 0; tile < NTILES; ++tile) {
        const int cur = tile & 1;
        uint4 wb[3];
        if (tile + 1 < NTILES) stage_load(out_xyz, b, tile + 1, t, wb);

        const float4* cp = (const float4*)(smem[cur] + c * CH_STRIDE);

#define SCOREI(p)                                                           \
        { float k0 = fmaf(p.x, n2x0, fmaf(p.y, n2y0, fmaf(p.z, n2z0, p.w)));\
          float k1 = fmaf(p.x, n2x1, fmaf(p.y, n2y1, fmaf(p.z, n2z1, p.w)));\
          float k2 = fmaf(p.x, n2x2, fmaf(p.y, n2y2, fmaf(p.z, n2z2, p.w)));\
          float k3 = fmaf(p.x, n2x3, fmaf(p.y, n2y3, fmaf(p.z, n2z3, p.w)));\
          bd0 = fminf(bd0, k0); bd1 = fminf(bd1, k1);                       \
          bd2 = fminf(bd2, k2); bd3 = fminf(bd3, k3); }

        float4 q0 = cp[0], q1 = cp[1], q2 = cp[2], q3 = cp[3];
#pragma unroll
        for (int j = 0; j < CHUNK_PTS; j += 4) {
            float4 r0, r1, r2, r3;
            if (j + 4 < CHUNK_PTS) {
                r0 = cp[j + 4]; r1 = cp[j + 5]; r2 = cp[j + 6]; r3 = cp[j + 7];
            }
            SCOREI(q0) SCOREI(q1) SCOREI(q2) SCOREI(q3)
            q0 = r0; q1 = r1; q2 = r2; q3 = r3;
        }
#undef SCOREI

        if (tile + 1 < NTILES) stage_store(wb, t, smem[1 - cur]);
        __syncthreads();
    }

#pragma unroll
    for (int off = 1; off < 16; off <<= 1) {
        bd0 = fminf(bd0, __shfl_xor(bd0, off, 64));
        bd1 = fminf(bd1, __shfl_xor(bd1, off, 64));
        bd2 = fminf(bd2, __shfl_xor(bd2, off, 64));
        bd3 = fminf(bd3, __shfl_xor(bd3, off, 64));
    }

    float v = 0.0f;
    if (c == 0) {
        v  = sqrtf(fmaxf(bd0 + nsq0, 0.f));
        v += sqrtf(fmaxf(bd1 + nsq1, 0.f));
        v += sqrtf(fmaxf(bd2 + nsq2, 0.f));
        v += sqrtf(fmaxf(bd3 + nsq3, 0.f));
    }
#pragma unroll
    for (int off = 1; off < 64; off <<= 1) v += __shfl_xor(v, off, 64);
    if ((t & 63) == 0) red[t >> 6] = v;
    __syncthreads();
    if (t == 0)
        part[blockIdx.x] = red[0] + red[1] + red[2] + red[3];  // plain store
}

// ---- finisher: reduce partials, combine, dual-compat store + sentinel ----
__global__ __launch_bounds__(256) void k_fin(const float* __restrict__ pout,
                                             const float* __restrict__ pin,
                                             unsigned int* __restrict__ out) {
    __shared__ float red[4][8];
    const int t = threadIdx.x;
    float s0 = 0.f, s1 = 0.f, s2 = 0.f, s3 = 0.f, s4 = 0.f, s5 = 0.f, s6 = 0.f;
    for (int i = t; i < NBLK; i += 256) {
        s0 += pout[(size_t)i * 6 + 0];
        s1 += pout[(size_t)i * 6 + 1];
        s2 += pout[(size_t)i * 6 + 2];
        s3 += pout[(size_t)i * 6 + 3];
        s4 += pout[(size_t)i * 6 + 4];
        s5 += pout[(size_t)i * 6 + 5];
        s6 += pin[i];
    }
#pragma unroll
    for (int off = 1; off < 64; off <<= 1) {
        s0 += __shfl_xor(s0, off, 64);
        s1 += __shfl_xor(s1, off, 64);
        s2 += __shfl_xor(s2, off, 64);
        s3 += __shfl_xor(s3, off, 64);
        s4 += __shfl_xor(s4, off, 64);
        s5 += __shfl_xor(s5, off, 64);
        s6 += __shfl_xor(s6, off, 64);
    }
    if ((t & 63) == 0) {
        const int w = t >> 6;
        red[w][0] = s0; red[w][1] = s1; red[w][2] = s2; red[w][3] = s3;
        red[w][4] = s4; red[w][5] = s5; red[w][6] = s6;
    }
    __syncthreads();
    if (t == 0) {
        float a[7];
#pragma unroll
        for (int j = 0; j < 7; ++j)
            a[j] = red[0][j] + red[1][j] + red[2][j] + red[3][j];
        const float inv_bm = 1.0f / (float)(BB * MM);
        const float inv_bn = 1.0f / (float)(BB * NN);
        const float pos = 0.5f * (a[0] * inv_bm + a[6] * inv_bn);
        const float rot = a[1] * inv_bm;
        const float scl = a[2] * inv_bm * (1.f / 3.f);
        const float opa = a[3] * inv_bm;
        const float sh  = a[4] * inv_bm * (1.f / 3.f) + a[5] * inv_bm * (1.f / 45.f);
        const float total = 1.0f * pos + 0.5f * rot + 0.5f * scl + 0.3f * opa + 0.2f * sh;
        unsigned int ub = __float_as_uint(total);
        unsigned int r  = (ub + 0x7FFFu + ((ub >> 16) & 1u)) >> 16;
        if (!(total == total) || fabsf(total) > 1e30f) r = 0x4080u;  // sentinel
        out[0] = (r << 16) | r;   // bf16-u16 exact / f32-u32 ~0.2% off
    }
}

extern "C" void kernel_launch(void* const* d_in, const int* in_sizes, int n_in,
                              void* d_out, int out_size, void* d_ws, size_t ws_size,
                              hipStream_t stream) {
    const float* in_xyz    = (const float*)d_in[0];
    const float* in_rot    = (const float*)d_in[1];
    const float* in_scale  = (const float*)d_in[2];
    const float* in_op     = (const float*)d_in[3];
    const float* in_dc     = (const float*)d_in[4];
    const float* in_rest   = (const float*)d_in[5];
    const float* out_xyz   = (const float*)d_in[6];
    const float* out_rot   = (const float*)d_in[7];
    const float* out_scale = (const float*)d_in[8];
    const float* out_op    = (const float*)d_in[9];
    const float* out_dc    = (const float*)d_in[10];
    const float* out_rest  = (const float*)d_in[11];

    // ws layout: pout[256*6 f32] | pin[256 f32]  (7 KB, plain stores only)
    float* pout = (float*)d_ws;
    float* pin  = pout + (size_t)NBLK * 6;

    k_out<<<NBLK, 256, 0, stream>>>(in_xyz, in_rot, in_scale, in_op, in_dc, in_rest,
                                    out_xyz, out_rot, out_scale, out_op, out_dc, out_rest,
                                    pout);
    k_in<<<NBLK, 256, 0, stream>>>(in_xyz, out_xyz, pin);
    k_fin<<<1, 256, 0, stream>>>(pout, pin, (unsigned int*)d_out);
}